// Round 11
// baseline (391.269 us; speedup 1.0000x reference)
//
#include <hip/hip_runtime.h>
#include <hip/hip_bf16.h>

// Sizes fixed by the reference problem.
#define CN 32
#define RN 256
#define DN 512
#define NN 32
#define LN 256

// LDS layout of main kernel (bytes):
//  sAt   : bf16 [256][256] = 131072, 16B-chunk XOR swizzle
//  stage : 32768 = double-buffered staging (conS / Gs), 16K per buffer.
//    Overlays (barrier-ordered into dead regions):
//      ssP  @ +0     [256][2] f32   denP @ +2048 [256][2] f32
//      red  @ +8192  [8] f32        w12P @ +16384 [256][4] f32
//      nsqP @ +0     [256][2] f32 (after phase-B k-loop + barrier)
//  total : 163840 = 160 KiB (1 block/CU, 8 waves, 2 waves/SIMD, 256-reg
//          budget -> no spills; R8/R10 proved 128-reg budgets spill)
#define STAGE_OFF 131072
#define SMEM_TOTAL 163840

typedef short v8s __attribute__((ext_vector_type(8)));
typedef float v4f __attribute__((ext_vector_type(4)));
typedef const __attribute__((address_space(1))) void* gas1_t;
typedef __attribute__((address_space(3))) void* las3_t;

__device__ __forceinline__ void gl2lds16(const void* g, void* l) {
  __builtin_amdgcn_global_load_lds((gas1_t)g, (las3_t)l, 16, 0, 0);
}

__device__ __forceinline__ unsigned short f2bf(float x) {
  unsigned int u = __float_as_uint(x);
  u = (u + 0x7fffu + ((u >> 16) & 1u)) >> 16;  // RNE
  return (unsigned short)u;
}
__device__ __forceinline__ float bf2f(unsigned short h) {
  return __uint_as_float(((unsigned int)h) << 16);
}

// Staging buffers ([256][32] shorts): 16B chunks XOR-swizzled with (r>>1)&3.
// Writes absorb the swizzle in the global fetch column; reads via this helper.
__device__ __forceinline__ const v8s* stgFrag(const unsigned short* buf, int r,
                                              int quad) {
  return (const v8s*)(buf + r * 32 + ((quad ^ ((r >> 1) & 3)) << 3));
}

// sAt addressing: row-major stride 256 shorts, 16B chunks XOR-swizzled by row.
__device__ __forceinline__ int satIdx(int r, int col) {
  return (r << 8) | ((((col >> 3) ^ (r & 7)) << 3) | (col & 7));
}

// ---------------------------------------------------------------------------
// Prep: fp32 -> bf16 copies of laws & contracts, plus ||contracts[c,r,:]||.
// ---------------------------------------------------------------------------
__global__ __launch_bounds__(256) void prep_kernel(
    const float* __restrict__ con, const float* __restrict__ laws,
    unsigned short* __restrict__ lawsB, unsigned short* __restrict__ conB,
    float* __restrict__ cnorm) {
  const int bid = blockIdx.x;
  const int t = threadIdx.x;
  if (bid < 2048) {
    const int r = bid * 4 + (t >> 6);
    const int lane = t & 63;
    const float4* src = (const float4*)(con + r * DN + lane * 8);
    float4 x0 = src[0], x1 = src[1];
    unsigned short h[8];
    h[0] = f2bf(x0.x); h[1] = f2bf(x0.y); h[2] = f2bf(x0.z); h[3] = f2bf(x0.w);
    h[4] = f2bf(x1.x); h[5] = f2bf(x1.y); h[6] = f2bf(x1.z); h[7] = f2bf(x1.w);
    *(v8s*)(conB + r * DN + lane * 8) = *(v8s*)h;
    float s = x0.x * x0.x + x0.y * x0.y + x0.z * x0.z + x0.w * x0.w +
              x1.x * x1.x + x1.y * x1.y + x1.z * x1.z + x1.w * x1.w;
#pragma unroll
    for (int m = 1; m < 64; m <<= 1) s += __shfl_xor(s, m, 64);
    if (lane == 0) cnorm[r] = sqrtf(s);
  } else {
    const int off = (bid - 2048) * 2048 + t * 8;
    const float4* src = (const float4*)(laws + off);
    float4 x0 = src[0], x1 = src[1];
    unsigned short h[8];
    h[0] = f2bf(x0.x); h[1] = f2bf(x0.y); h[2] = f2bf(x0.z); h[3] = f2bf(x0.w);
    h[4] = f2bf(x1.x); h[5] = f2bf(x1.y); h[6] = f2bf(x1.z); h[7] = f2bf(x1.w);
    *(v8s*)(lawsB + off) = *(v8s*)h;
  }
}

// ---------------------------------------------------------------------------
// Gram via MFMA. 256 blocks = (n, 32-row stripe) -> all CUs busy.
// ---------------------------------------------------------------------------
__global__ __launch_bounds__(512) void gramm_kernel(
    const unsigned short* __restrict__ lawsB, unsigned short* __restrict__ G) {
  __shared__ unsigned short slice[256 * 32];  // 16 KB
  const int bx = blockIdx.x;
  const int n = bx >> 3;
  const int m0 = (bx & 7) << 5;
  const int t = threadIdx.x;
  const int lane = t & 63;
  const int w = t >> 6;
  const int quad = lane >> 4;
  const int l16 = lane & 15;
  const int sub = t & 3;
  const int rQ = t >> 2;
  const int subx = sub ^ ((rQ >> 1) & 3);
  const int rg = w >> 2;  // 0..1
  const int cg = w & 3;   // 0..3
  const unsigned short* lawN = lawsB + n * (LN * DN);

  v4f acc[4];
#pragma unroll
  for (int b = 0; b < 4; ++b) acc[b] = (v4f){0.f, 0.f, 0.f, 0.f};

  for (int ch = 0; ch < 16; ++ch) {
    const int dk = ch << 5;
    __syncthreads();
#pragma unroll
    for (int i = 0; i < 2; ++i)
      gl2lds16(lawN + (i * 128 + rQ) * DN + dk + subx * 8,
               (char*)slice + i * 8192 + t * 16);
    __syncthreads();
    v8s af = *stgFrag(slice, m0 + rg * 16 + l16, quad);
#pragma unroll
    for (int ct = 0; ct < 4; ++ct) {
      v8s bf = *stgFrag(slice, cg * 64 + ct * 16 + l16, quad);
      acc[ct] = __builtin_amdgcn_mfma_f32_16x16x32_bf16(af, bf, acc[ct], 0, 0, 0);
    }
  }
  unsigned short* g = G + n * (LN * LN);
#pragma unroll
  for (int ct = 0; ct < 4; ++ct)
#pragma unroll
    for (int reg = 0; reg < 4; ++reg) {
      const int l = m0 + rg * 16 + quad * 4 + reg;
      g[l * LN + cg * 64 + ct * 16 + l16] = f2bf(acc[ct][reg]);
    }
}

// ---------------------------------------------------------------------------
// Main: one block per (n,c), 512 threads = 8 waves arranged 4x2:
// phase A wave tile 64l x 128r (acc[4][8] = 128 AGPR), phase B 64r x 128l'.
// Per chunk per wave: 8 staged B-frag LDS reads + 4 direct-global A-frags
// (vs 16+2 in the 32x256 layout) -> per-CU LDS read traffic cut 2.25x (the
// measured limiter). conS/Gs double-buffered, 1 barrier/chunk (R6 pipeline).
// Cross-wave softmax/w12/nsq partials in LDS overlays (R10-proven sequence).
// ---------------------------------------------------------------------------
__global__ __launch_bounds__(512, 2) void main_kernel(
    const int* __restrict__ law_lens, const unsigned short* __restrict__ lawsB,
    const unsigned short* __restrict__ conB, const unsigned short* __restrict__ Gm,
    const float* __restrict__ cnorm, float* __restrict__ out) {
  extern __shared__ char smem[];
  unsigned short* sAt = (unsigned short*)smem;  // [256][256] swizzled
  char* stage = smem + STAGE_OFF;               // 2 x 16K buffers

  const int bid = blockIdx.x;
  const int n = bid >> 5;  // 32 consecutive blocks share one n
  const int c = bid & 31;
  const int t = threadIdx.x;
  const int lane = t & 63;
  const int w = t >> 6;  // wave 0..7
  const int quad = lane >> 4;
  const int l16 = lane & 15;
  const int sub = t & 3;
  const int rQ = t >> 2;                   // 0..127
  const int subx = sub ^ ((rQ >> 1) & 3);  // swizzled source chunk
  const int lgroup = w >> 1;               // phase A: l rows lgroup*64..+63
  const int rgroup = w & 1;                // phase A: r cols rgroup*128..+127
  const int len = law_lens[n];
  const int nCh = (len + 31) >> 5;         // phase-B k-chunks (block-uniform)
  const float kInv = 0.04419417382415922f;  // 1/sqrt(512)

  const unsigned short* lawN = lawsB + n * (LN * DN);
  const unsigned short* conC = conB + c * (RN * DN);
  const unsigned short* Gn = Gm + n * (LN * LN);

  float* ssP = (float*)stage;             // [256][2]
  float* denP = (float*)(stage + 2048);   // [256][2]
  float* red = (float*)(stage + 8192);    // [8]
  float* w12P = (float*)(stage + 16384);  // [256][4] (buf1 region)
  float* nsqP = (float*)stage;            // [256][2] (phase-B epilogue)

  // ---------------- Phase A: S = laws @ con^T ----------------
  v4f acc[4][8];  // [lt][ct] : 64l x 128r wave tile, 128 AGPR
#pragma unroll
  for (int a = 0; a < 4; ++a)
#pragma unroll
    for (int b = 0; b < 8; ++b) acc[a][b] = (v4f){0.f, 0.f, 0.f, 0.f};

  const unsigned short* afp = lawN + (lgroup * 64 + l16) * DN + quad * 8;

  // Prologue: stage con chunk 0 into buf0.
#pragma unroll
  for (int i = 0; i < 2; ++i)
    gl2lds16(conC + (i * 128 + rQ) * DN + subx * 8, stage + i * 8192 + t * 16);

  for (int ch = 0; ch < 16; ++ch) {
    const int dk = ch << 5;
    __syncthreads();  // drains chunk-ch staging (in flight since iter ch-1)
    v8s af[4];        // direct-global A-frags (L2-hot; older than prefetch)
#pragma unroll
    for (int lt = 0; lt < 4; ++lt)
      af[lt] = *(const v8s*)(afp + lt * (16 * DN) + dk);
    __builtin_amdgcn_sched_barrier(0);
    if (ch < 15) {  // prefetch chunk ch+1 into the other buffer
      char* dst = stage + ((ch + 1) & 1) * 16384;
#pragma unroll
      for (int i = 0; i < 2; ++i)
        gl2lds16(conC + (i * 128 + rQ) * DN + (dk + 32) + subx * 8,
                 dst + i * 8192 + t * 16);
    }
    __builtin_amdgcn_sched_barrier(0);
    const unsigned short* cs = (const unsigned short*)(stage + (ch & 1) * 16384);
#pragma unroll
    for (int ct = 0; ct < 8; ++ct) {
      v8s bf = *stgFrag(cs, rgroup * 128 + ct * 16 + l16, quad);
#pragma unroll
      for (int lt = 0; lt < 4; ++lt)
        acc[lt][ct] = __builtin_amdgcn_mfma_f32_16x16x32_bf16(af[lt], bf, acc[lt][ct], 0, 0, 0);
    }
  }
  __syncthreads();  // all staged reads done; overlays usable

  // Softmax pass 1: per-l-row ss partials over this wave's 128 r.
#pragma unroll
  for (int lt = 0; lt < 4; ++lt)
#pragma unroll
    for (int reg = 0; reg < 4; ++reg) {
      float ssp = 0.f;
#pragma unroll
      for (int ct = 0; ct < 8; ++ct) {
        const float v = acc[lt][ct][reg] * kInv;
        const float lv = v > 0.f ? v : 0.1f * v;
        ssp += lv * lv;
      }
#pragma unroll
      for (int m = 1; m < 16; m <<= 1) ssp += __shfl_xor(ssp, m, 64);
      if (l16 == 0)
        ssP[(lgroup * 64 + lt * 16 + quad * 4 + reg) * 2 + rgroup] = ssp;
    }
  __syncthreads();

  // Pass 2: den partials (|lv*inv| <= 1 -> exp in [1/e, e], no max needed).
#pragma unroll
  for (int lt = 0; lt < 4; ++lt)
#pragma unroll
    for (int reg = 0; reg < 4; ++reg) {
      const int row = lgroup * 64 + lt * 16 + quad * 4 + reg;
      const float2 s2 = *(const float2*)&ssP[row * 2];
      const float inv = 1.f / (sqrtf(s2.x + s2.y) + 1e-8f);
      float dnp = 0.f;
#pragma unroll
      for (int ct = 0; ct < 8; ++ct) {
        const float v = acc[lt][ct][reg] * kInv;
        const float lv = v > 0.f ? v : 0.1f * v;
        dnp += __expf(lv * inv);
      }
#pragma unroll
      for (int m = 1; m < 16; m <<= 1) dnp += __shfl_xor(dnp, m, 64);
      if (l16 == 0) denP[row * 2 + rgroup] = dnp;
    }
  __syncthreads();

  // Pass 3: emit attn -> sAt (packed b64), accumulate w12 per r-col.
  float w12c[8] = {0.f, 0.f, 0.f, 0.f, 0.f, 0.f, 0.f, 0.f};
#pragma unroll
  for (int lt = 0; lt < 4; ++lt) {
    const int row0 = lgroup * 64 + lt * 16 + quad * 4;
    float invv[4], scv[4];
#pragma unroll
    for (int reg = 0; reg < 4; ++reg) {
      const float2 s2 = *(const float2*)&ssP[(row0 + reg) * 2];
      invv[reg] = 1.f / (sqrtf(s2.x + s2.y) + 1e-8f);
      const float2 d2 = *(const float2*)&denP[(row0 + reg) * 2];
      scv[reg] = (row0 + reg < len) ? 4.f / (d2.x + d2.y) : 0.f;
    }
#pragma unroll
    for (int ct = 0; ct < 8; ++ct) {
      unsigned int p0 = 0, p1 = 0;
#pragma unroll
      for (int reg = 0; reg < 4; ++reg) {
        const float v = acc[lt][ct][reg] * kInv;
        const float lv = v > 0.f ? v : 0.1f * v;
        const float a = __expf(lv * invv[reg]) * scv[reg];
        w12c[ct] += a * v;  // raw S -> cosine numerator (fp32 exact)
        const unsigned int h = f2bf(a);
        if (reg == 0) p0 = h;
        else if (reg == 1) p0 |= h << 16;
        else if (reg == 2) p1 = h;
        else p1 |= h << 16;
      }
      uint2 pk; pk.x = p0; pk.y = p1;
      *(uint2*)(sAt + satIdx(rgroup * 128 + ct * 16 + l16, row0)) = pk;
    }
  }
  // w12: sum across quads (l pieces), publish per (r-col, lgroup).
#pragma unroll
  for (int ct = 0; ct < 8; ++ct) {
    w12c[ct] += __shfl_xor(w12c[ct], 16, 64);
    w12c[ct] += __shfl_xor(w12c[ct], 32, 64);
  }
  if (quad == 0) {
#pragma unroll
    for (int ct = 0; ct < 8; ++ct)
      w12P[(rgroup * 128 + ct * 16 + l16) * 4 + lgroup] = w12c[ct];
  }
  __syncthreads();  // sAt + w12P visible; ssP/denP dead

  float w12f = 0.f;
  if (t < 256) {
    const float4 q = *(const float4*)&w12P[t * 4];
    w12f = q.x + q.y + q.z + q.w;  // held in a register through phase B
  }

  // Prologue: stage G chunk 0 into buf0 (clobbers dead ssP/denP only).
#pragma unroll
  for (int i = 0; i < 2; ++i)
    gl2lds16(Gn + (i * 128 + rQ) * LN + subx * 8, stage + i * 8192 + t * 16);

  // ---------------- Phase B: U = At @ G, k capped at ceil(len/32) ---------
  const int rgB = w >> 1;  // r rows rgB*64..+63
  const int cgB = w & 1;   // l' cols cgB*128..+127
  v4f accB[4][8];          // [rt][ct]
#pragma unroll
  for (int a = 0; a < 4; ++a)
#pragma unroll
    for (int b = 0; b < 8; ++b) accB[a][b] = (v4f){0.f, 0.f, 0.f, 0.f};

  for (int ch = 0; ch < nCh; ++ch) {
    const int lk = ch << 5;
    __syncthreads();  // drains chunk-ch Gs staging; ch0: orders w12f reads
    v8s afv[4];
#pragma unroll
    for (int rt = 0; rt < 4; ++rt)
      afv[rt] = *(const v8s*)(sAt + satIdx(rgB * 64 + rt * 16 + l16, lk + quad * 8));
    __builtin_amdgcn_sched_barrier(0);
    if (ch < nCh - 1) {  // prefetch chunk ch+1
      char* dst = stage + ((ch + 1) & 1) * 16384;
#pragma unroll
      for (int i = 0; i < 2; ++i)
        gl2lds16(Gn + (i * 128 + rQ) * LN + (lk + 32) + subx * 8,
                 dst + i * 8192 + t * 16);
    }
    __builtin_amdgcn_sched_barrier(0);
    const unsigned short* gs = (const unsigned short*)(stage + (ch & 1) * 16384);
#pragma unroll
    for (int ct = 0; ct < 8; ++ct) {
      v8s bf = *stgFrag(gs, cgB * 128 + ct * 16 + l16, quad);  // G row (sym)
#pragma unroll
      for (int rt = 0; rt < 4; ++rt)
        accB[rt][ct] = __builtin_amdgcn_mfma_f32_16x16x32_bf16(afv[rt], bf, accB[rt][ct], 0, 0, 0);
    }
  }
  __syncthreads();  // all Gs reads done; nsqP region free

  // nsq partials: sum_{l'} At[r,l'] U[r,l'] over this wave's 128 l'.
#pragma unroll
  for (int rt = 0; rt < 4; ++rt)
#pragma unroll
    for (int reg = 0; reg < 4; ++reg) {
      const int row = rgB * 64 + rt * 16 + quad * 4 + reg;
      float s = 0.f;
#pragma unroll
      for (int ct = 0; ct < 8; ++ct)
        s += accB[rt][ct][reg] * bf2f(sAt[satIdx(row, cgB * 128 + ct * 16 + l16)]);
#pragma unroll
      for (int m = 1; m < 16; m <<= 1) s += __shfl_xor(s, m, 64);
      if (l16 == 0) nsqP[row * 2 + cgB] = s;
    }
  __syncthreads();

  // ---------------- Phase C ----------------
  float p = 0.f;
  if (t < 256) {
    const float2 q = *(const float2*)&nsqP[t * 2];
    const float nsq = q.x + q.y;
    const float w1 = cnorm[c * RN + t];
    const float w2 = sqrtf(fmaxf(nsq, 0.f));
    const float sim = (w12f * 22.627416997969522f) / fmaxf(w1 * w2, 1e-8f);
    p = __expf(6.f * sim);
  }
#pragma unroll
  for (int m = 1; m < 64; m <<= 1) p += __shfl_xor(p, m, 64);
  if (lane == 0) red[w] = p;
  __syncthreads();
  if (t == 0) {
    float s = 0.f;
#pragma unroll
    for (int i = 0; i < 8; ++i) s += red[i];
    out[c * NN + n] = logf(s) / 6.f;
  }
}

// ---------------------------------------------------------------------------
extern "C" void kernel_launch(void* const* d_in, const int* in_sizes, int n_in,
                              void* d_out, int out_size, void* d_ws, size_t ws_size,
                              hipStream_t stream) {
  (void)in_sizes; (void)n_in; (void)out_size;
  const float* contracts = (const float*)d_in[0];
  const float* laws = (const float*)d_in[1];
  const int* law_lens = (const int*)d_in[2];
  float* out = (float*)d_out;

  // Workspace layout (21,004,288 B total)
  unsigned short* lawsB = (unsigned short*)d_ws;  // 8 MiB
  unsigned short* conB = lawsB + NN * LN * DN;    // 8 MiB
  unsigned short* G = conB + CN * RN * DN;        // 4 MiB
  float* cnorm = (float*)(G + NN * LN * LN);      // 32 KiB
  if (ws_size < (size_t)21004288) return;

  hipFuncSetAttribute((const void*)main_kernel,
                      hipFuncAttributeMaxDynamicSharedMemorySize, SMEM_TOTAL);

  prep_kernel<<<4096, 256, 0, stream>>>(contracts, laws, lawsB, conB, cnorm);
  gramm_kernel<<<256, 512, 0, stream>>>(lawsB, G);
  main_kernel<<<1024, 512, SMEM_TOTAL, stream>>>(law_lens, lawsB, conB, G,
                                                 cnorm, out);
}

// Round 12
// 247.941 us; speedup vs baseline: 1.5781x; 1.5781x over previous
//
#include <hip/hip_runtime.h>
#include <hip/hip_bf16.h>

// Sizes fixed by the reference problem.
#define CN 32
#define RN 256
#define DN 512
#define NN 32
#define LN 256

// LDS layout of main kernel (bytes):
//  sAt   : bf16 [256][256] = 131072, 16B-chunk XOR swizzle (chunk ^= r&7)
//  stage : 32768 = double-buffered staging (conS / Gs), 16K per buffer.
//          Epilogue reductions (w12s 8K, nsqS 1K, red) overlay this region.
//  total : 163840 = 160 KiB (1 block/CU, 8 waves, 2 waves/SIMD, 256-reg
//          budget; R8/R10/R11 proved bigger tiles spill at every occupancy)
#define STAGE_OFF 131072
#define SMEM_TOTAL 163840

typedef short v8s __attribute__((ext_vector_type(8)));
typedef float v4f __attribute__((ext_vector_type(4)));
typedef const __attribute__((address_space(1))) void* gas1_t;
typedef __attribute__((address_space(3))) void* las3_t;

__device__ __forceinline__ void gl2lds16(const void* g, void* l) {
  __builtin_amdgcn_global_load_lds((gas1_t)g, (las3_t)l, 16, 0, 0);
}

__device__ __forceinline__ unsigned short f2bf(float x) {
  unsigned int u = __float_as_uint(x);
  u = (u + 0x7fffu + ((u >> 16) & 1u)) >> 16;  // RNE
  return (unsigned short)u;
}
__device__ __forceinline__ float bf2f(unsigned short h) {
  return __uint_as_float(((unsigned int)h) << 16);
}

// Staging buffers ([256][32] shorts): 16B chunks XOR-swizzled with (r>>1)&3.
// Writes absorb the swizzle in the global fetch column; reads via this helper.
__device__ __forceinline__ const v8s* stgFrag(const unsigned short* buf, int r,
                                              int quad) {
  return (const v8s*)(buf + r * 32 + ((quad ^ ((r >> 1) & 3)) << 3));
}

// sAt addressing: row-major stride 256 shorts, 16B chunks XOR-swizzled by row.
__device__ __forceinline__ int satIdx(int r, int col) {
  return (r << 8) | ((((col >> 3) ^ (r & 7)) << 3) | (col & 7));
}

// Read an 8-float fragment from the fp32 gram slice (row-rotated by
// (quad+row)&3 in 8-float chunks) and convert to bf16x8.
__device__ __forceinline__ v8s ldFrag32(const float* buf, int r, int quad) {
  const float* p = buf + r * 32 + (((quad + r) & 3) << 3);
  const float4 x0 = ((const float4*)p)[0];
  const float4 x1 = ((const float4*)p)[1];
  unsigned short h[8];
  h[0] = f2bf(x0.x); h[1] = f2bf(x0.y); h[2] = f2bf(x0.z); h[3] = f2bf(x0.w);
  h[4] = f2bf(x1.x); h[5] = f2bf(x1.y); h[6] = f2bf(x1.z); h[7] = f2bf(x1.w);
  return *(v8s*)h;
}

// ---------------------------------------------------------------------------
// Fused setup (ONE launch, 512 threads/block, role by blockIdx):
//  blocks 0..255    : Gram G[n] = laws[n]@laws[n]^T (bf16 out), reading fp32
//                     laws staged through LDS via gl2lds (no dependency on
//                     the prep blocks; runs concurrently with them).
//  blocks 256..1279 : contracts fp32->bf16 (8 rows each) + row norms.
//  blocks 1280..2303: laws fp32->bf16 (4096 elements each).
// ---------------------------------------------------------------------------
__global__ __launch_bounds__(512) void setup_kernel(
    const float* __restrict__ con, const float* __restrict__ laws,
    unsigned short* __restrict__ lawsB, unsigned short* __restrict__ conB,
    float* __restrict__ cnorm, unsigned short* __restrict__ G) {
  const int bid = blockIdx.x;
  const int t = threadIdx.x;
  if (bid < 256) {
    // ---- Gram from fp32 laws, LDS-staged ----
    __shared__ float slice[256 * 32];  // 32 KB fp32, row-rotated chunks
    const int n = bid >> 3;
    const int m0 = (bid & 7) << 5;  // 32-row output stripe
    const int lane = t & 63;
    const int w = t >> 6;
    const int quad = lane >> 4;
    const int l16 = lane & 15;
    const int rg = w >> 2;  // 0..1 (16-row half of the stripe)
    const int cg = w & 3;   // 0..3 (64-col group)
    const float* lawN = laws + n * (LN * DN);
    // Staging map: thread t writes LDS slot t*16 + i*8192 which is
    // (row = i*64 + t>>3, chunk c4 = (t>>1)&3, half = t&1); the rotation
    // means that slot holds source chunk (c4 - row)&3.
    const int srow = t >> 3;
    const int sc4 = (t >> 1) & 3;
    const int shalf = t & 1;

    v4f acc[4];
#pragma unroll
    for (int b = 0; b < 4; ++b) acc[b] = (v4f){0.f, 0.f, 0.f, 0.f};

    for (int ch = 0; ch < 16; ++ch) {
      const int dk = ch << 5;
      __syncthreads();
#pragma unroll
      for (int i = 0; i < 4; ++i) {
        const int row = i * 64 + srow;
        const int srcCol = (((sc4 - row) & 3) << 3) + (shalf << 2);
        gl2lds16(lawN + row * DN + dk + srcCol,
                 (char*)slice + i * 8192 + t * 16);
      }
      __syncthreads();
      v8s af = ldFrag32(slice, m0 + rg * 16 + l16, quad);
#pragma unroll
      for (int ct = 0; ct < 4; ++ct) {
        v8s bf = ldFrag32(slice, cg * 64 + ct * 16 + l16, quad);
        acc[ct] = __builtin_amdgcn_mfma_f32_16x16x32_bf16(af, bf, acc[ct], 0, 0, 0);
      }
    }
    unsigned short* g = G + n * (LN * LN);
#pragma unroll
    for (int ct = 0; ct < 4; ++ct)
#pragma unroll
      for (int reg = 0; reg < 4; ++reg) {
        const int l = m0 + rg * 16 + quad * 4 + reg;
        g[l * LN + cg * 64 + ct * 16 + l16] = f2bf(acc[ct][reg]);
      }
  } else if (bid < 1280) {
    // ---- contracts prep: 8 rows/block, one wave per row ----
    const int r = (bid - 256) * 8 + (t >> 6);
    const int lane = t & 63;
    const float4* src = (const float4*)(con + r * DN + lane * 8);
    float4 x0 = src[0], x1 = src[1];
    unsigned short h[8];
    h[0] = f2bf(x0.x); h[1] = f2bf(x0.y); h[2] = f2bf(x0.z); h[3] = f2bf(x0.w);
    h[4] = f2bf(x1.x); h[5] = f2bf(x1.y); h[6] = f2bf(x1.z); h[7] = f2bf(x1.w);
    *(v8s*)(conB + r * DN + lane * 8) = *(v8s*)h;
    float s = x0.x * x0.x + x0.y * x0.y + x0.z * x0.z + x0.w * x0.w +
              x1.x * x1.x + x1.y * x1.y + x1.z * x1.z + x1.w * x1.w;
#pragma unroll
    for (int m = 1; m < 64; m <<= 1) s += __shfl_xor(s, m, 64);
    if (lane == 0) cnorm[r] = sqrtf(s);
  } else {
    // ---- laws prep: 4096 floats/block ----
    const int off = (bid - 1280) * 4096 + t * 8;
    const float4* src = (const float4*)(laws + off);
    float4 x0 = src[0], x1 = src[1];
    unsigned short h[8];
    h[0] = f2bf(x0.x); h[1] = f2bf(x0.y); h[2] = f2bf(x0.z); h[3] = f2bf(x0.w);
    h[4] = f2bf(x1.x); h[5] = f2bf(x1.y); h[6] = f2bf(x1.z); h[7] = f2bf(x1.w);
    *(v8s*)(lawsB + off) = *(v8s*)h;
  }
}

// ---------------------------------------------------------------------------
// Main: one block per (n,c), 512 threads (8 waves). R6 pipelined structure
// (proven 177 us, no fatal spill) + ONE change: phase-B k-loop and staging
// capped at nCh = ceil(len/32) chunks (block-uniform; At == 0 beyond len,
// so skipped chunks contribute exactly zero).
// Phase A: S = laws[n]@con[c]^T; con staged via gl2lds dbuf (1 barrier per
//          chunk, prefetch overlaps compute); A-frags direct global;
//          softmax rows in-reg -> sAt bf16; w12 partials in registers.
// Phase B: U = At@G, G staged dbuf; nsq[r] = sum_l At[r,l]U[r,l].
// Phase C: sim = sqrt(D)*w12/(w1*w2); out[c,n] = LSE_6 over r.
// ---------------------------------------------------------------------------
__global__ __launch_bounds__(512, 2) void main_kernel(
    const int* __restrict__ law_lens, const unsigned short* __restrict__ lawsB,
    const unsigned short* __restrict__ conB, const unsigned short* __restrict__ Gm,
    const float* __restrict__ cnorm, float* __restrict__ out) {
  extern __shared__ char smem[];
  unsigned short* sAt = (unsigned short*)smem;  // [256][256] swizzled
  char* stage = smem + STAGE_OFF;               // 2 x 16K buffers

  const int bid = blockIdx.x;
  const int n = bid >> 5;  // 32 consecutive blocks share one n
  const int c = bid & 31;
  const int t = threadIdx.x;
  const int lane = t & 63;
  const int w = t >> 6;  // wave 0..7
  const int quad = lane >> 4;
  const int l16 = lane & 15;
  const int sub = t & 3;
  const int rQ = t >> 2;                   // 0..127
  const int subx = sub ^ ((rQ >> 1) & 3);  // swizzled source chunk
  const int len = law_lens[n];
  const int nCh = (len + 31) >> 5;         // phase-B k-chunks (block-uniform)

  const unsigned short* lawN = lawsB + n * (LN * DN);
  const unsigned short* conC = conB + c * (RN * DN);
  const unsigned short* Gn = Gm + n * (LN * LN);

  float w12p[16];
#pragma unroll
  for (int i = 0; i < 16; ++i) w12p[i] = 0.f;

  // ---------------- Phase A ----------------
  {
    const unsigned short* a0p = lawN + (w * 32 + l16) * DN + quad * 8;
    const unsigned short* a1p = a0p + 16 * DN;

    v4f acc[2][16];
#pragma unroll
    for (int a = 0; a < 2; ++a)
#pragma unroll
      for (int b = 0; b < 16; ++b) acc[a][b] = (v4f){0.f, 0.f, 0.f, 0.f};

    // Prologue: stage con chunk 0 into buf0.
#pragma unroll
    for (int i = 0; i < 2; ++i)
      gl2lds16(conC + (i * 128 + rQ) * DN + subx * 8,
               stage + i * 8192 + t * 16);

    for (int ch = 0; ch < 16; ++ch) {
      const int dk = ch << 5;
      __syncthreads();  // drains chunk-ch staging (in flight since iter ch-1)
      // A-frags FIRST (older than prefetch -> auto-wait becomes vmcnt(2)).
      v8s af0 = *(const v8s*)(a0p + dk);
      v8s af1 = *(const v8s*)(a1p + dk);
      __builtin_amdgcn_sched_barrier(0);
      if (ch < 15) {  // prefetch chunk ch+1 into the other buffer
        char* dst = stage + ((ch + 1) & 1) * 16384;
#pragma unroll
        for (int i = 0; i < 2; ++i)
          gl2lds16(conC + (i * 128 + rQ) * DN + (dk + 32) + subx * 8,
                   dst + i * 8192 + t * 16);
      }
      __builtin_amdgcn_sched_barrier(0);
      const unsigned short* cs =
          (const unsigned short*)(stage + (ch & 1) * 16384);
#pragma unroll
      for (int rt = 0; rt < 16; ++rt) {
        v8s bf = *stgFrag(cs, rt * 16 + l16, quad);
        acc[0][rt] = __builtin_amdgcn_mfma_f32_16x16x32_bf16(af0, bf, acc[0][rt], 0, 0, 0);
        acc[1][rt] = __builtin_amdgcn_mfma_f32_16x16x32_bf16(af1, bf, acc[1][rt], 0, 0, 0);
      }
    }
    // Row ops: row l lives in 16 lanes (C layout col=lane&15 -> r index).
    // 4 regs of a tile = 4 consecutive sAt columns -> packed b64 writes.
#pragma unroll
    for (int tl = 0; tl < 2; ++tl) {
      unsigned int pk[16][2];
#pragma unroll
      for (int reg = 0; reg < 4; ++reg) {
        const int lg = w * 32 + tl * 16 + quad * 4 + reg;
        float v[16], lv[16];
        float ss = 0.f;
#pragma unroll
        for (int rt = 0; rt < 16; ++rt) {
          v[rt] = acc[tl][rt][reg] * 0.04419417382415922f;  // 1/sqrt(512)
          lv[rt] = v[rt] > 0.f ? v[rt] : 0.1f * v[rt];
          ss += lv[rt] * lv[rt];
        }
#pragma unroll
        for (int m = 1; m < 16; m <<= 1) ss += __shfl_xor(ss, m, 64);
        const float inv = 1.f / (sqrtf(ss) + 1e-8f);
        float e[16];
        float den = 0.f;
#pragma unroll
        for (int rt = 0; rt < 16; ++rt) {
          e[rt] = __expf(lv[rt] * inv);  // |lv*inv| <= 1, no max needed
          den += e[rt];
        }
#pragma unroll
        for (int m = 1; m < 16; m <<= 1) den += __shfl_xor(den, m, 64);
        const float sc = (lg < len) ? 4.f / den : 0.f;  // SMOOTH, masked
#pragma unroll
        for (int rt = 0; rt < 16; ++rt) {
          const float a = e[rt] * sc;
          w12p[rt] += a * v[rt];  // raw S -> cosine numerator
          const unsigned int h = f2bf(a);
          if (reg & 1)
            pk[rt][reg >> 1] |= h << 16;
          else
            pk[rt][reg >> 1] = h;
        }
      }
      const int lg0 = w * 32 + tl * 16 + quad * 4;
#pragma unroll
      for (int rt = 0; rt < 16; ++rt)
        *(uint2*)(sAt + satIdx(rt * 16 + l16, lg0)) = *(uint2*)pk[rt];
    }
  }

  __syncthreads();  // sAt writes done (all waves); conS reads done

  // Prologue: stage G chunk 0 into buf0 (overlaps w12 shuffles below).
#pragma unroll
  for (int i = 0; i < 2; ++i)
    gl2lds16(Gn + (i * 128 + rQ) * LN + subx * 8, stage + i * 8192 + t * 16);

  // Reduce w12 partials across quads; keep in registers through phase B.
#pragma unroll
  for (int rt = 0; rt < 16; ++rt) {
    w12p[rt] += __shfl_xor(w12p[rt], 16, 64);
    w12p[rt] += __shfl_xor(w12p[rt], 32, 64);
  }

  // ---------------- Phase B (k capped at nCh = ceil(len/32)) ----------------
  float nsv[2][4];
  {
    v4f acc[2][16];
#pragma unroll
    for (int a = 0; a < 2; ++a)
#pragma unroll
      for (int b = 0; b < 16; ++b) acc[a][b] = (v4f){0.f, 0.f, 0.f, 0.f};

    for (int ch = 0; ch < nCh; ++ch) {
      const int lk = ch << 5;
      __syncthreads();  // drains chunk-ch Gs staging
      v8s af0 = *(const v8s*)(sAt + satIdx(w * 32 + l16, lk + quad * 8));
      v8s af1 = *(const v8s*)(sAt + satIdx(w * 32 + 16 + l16, lk + quad * 8));
      __builtin_amdgcn_sched_barrier(0);
      if (ch < nCh - 1) {  // prefetch chunk ch+1
        char* dst = stage + ((ch + 1) & 1) * 16384;
#pragma unroll
        for (int i = 0; i < 2; ++i)
          gl2lds16(Gn + (i * 128 + rQ) * LN + (lk + 32) + subx * 8,
                   dst + i * 8192 + t * 16);
      }
      __builtin_amdgcn_sched_barrier(0);
      const unsigned short* gs =
          (const unsigned short*)(stage + (ch & 1) * 16384);
#pragma unroll
      for (int lt = 0; lt < 16; ++lt) {
        v8s bf = *stgFrag(gs, lt * 16 + l16, quad);  // G row (symmetric)
        acc[0][lt] = __builtin_amdgcn_mfma_f32_16x16x32_bf16(af0, bf, acc[0][lt], 0, 0, 0);
        acc[1][lt] = __builtin_amdgcn_mfma_f32_16x16x32_bf16(af1, bf, acc[1][lt], 0, 0, 0);
      }
    }
    // nsq[r] = sum_l At[r,l] * U[r,l] (reads sAt + registers only)
#pragma unroll
    for (int tl = 0; tl < 2; ++tl) {
#pragma unroll
      for (int reg = 0; reg < 4; ++reg) {
        const int r = w * 32 + tl * 16 + quad * 4 + reg;
        float s = 0.f;
#pragma unroll
        for (int lt = 0; lt < 16; ++lt)
          s += acc[tl][lt][reg] * bf2f(sAt[satIdx(r, lt * 16 + l16)]);
#pragma unroll
        for (int m = 1; m < 16; m <<= 1) s += __shfl_xor(s, m, 64);
        nsv[tl][reg] = s;
      }
    }
  }

  // ---------------- Phase C (reductions overlay the stage region) ----------
  float* w12s = (float*)stage;           // [8][256] = 8K
  float* nsqS = (float*)(stage + 8192);  // [256]    = 1K
  float* red = (float*)(stage + 9216);   // [8]
  __syncthreads();  // all Gs reads done; stage is free for reductions
  if (l16 == 0) {
#pragma unroll
    for (int tl = 0; tl < 2; ++tl)
#pragma unroll
      for (int reg = 0; reg < 4; ++reg)
        nsqS[w * 32 + tl * 16 + quad * 4 + reg] = nsv[tl][reg];
  }
  if (lane < 16) {
#pragma unroll
    for (int rt = 0; rt < 16; ++rt) w12s[w * 256 + rt * 16 + lane] = w12p[rt];
  }
  __syncthreads();
  float p = 0.f;
  if (t < 256) {
    float w12 = 0.f;
#pragma unroll
    for (int i = 0; i < 8; ++i) w12 += w12s[i * 256 + t];
    const float w1 = cnorm[c * RN + t];
    const float w2 = sqrtf(fmaxf(nsqS[t], 0.f));
    const float sim = (w12 * 22.627416997969522f) / fmaxf(w1 * w2, 1e-8f);
    p = __expf(6.f * sim);
  }
#pragma unroll
  for (int m = 1; m < 64; m <<= 1) p += __shfl_xor(p, m, 64);
  if (lane == 0) red[w] = p;
  __syncthreads();
  if (t == 0) {
    float s = 0.f;
#pragma unroll
    for (int i = 0; i < 8; ++i) s += red[i];
    out[c * NN + n] = logf(s) / 6.f;
  }
}

// ---------------------------------------------------------------------------
extern "C" void kernel_launch(void* const* d_in, const int* in_sizes, int n_in,
                              void* d_out, int out_size, void* d_ws, size_t ws_size,
                              hipStream_t stream) {
  (void)in_sizes; (void)n_in; (void)out_size;
  const float* contracts = (const float*)d_in[0];
  const float* laws = (const float*)d_in[1];
  const int* law_lens = (const int*)d_in[2];
  float* out = (float*)d_out;

  // Workspace layout (21,004,288 B total)
  unsigned short* lawsB = (unsigned short*)d_ws;  // 8 MiB
  unsigned short* conB = lawsB + NN * LN * DN;    // 8 MiB
  unsigned short* G = conB + CN * RN * DN;        // 4 MiB
  float* cnorm = (float*)(G + NN * LN * LN);      // 32 KiB
  if (ws_size < (size_t)21004288) return;

  hipFuncSetAttribute((const void*)main_kernel,
                      hipFuncAttributeMaxDynamicSharedMemorySize, SMEM_TOTAL);

  // 256 gram + 1024 contracts-prep + 1024 laws-prep blocks, one launch.
  setup_kernel<<<2304, 512, 0, stream>>>(contracts, laws, lawsB, conB, cnorm,
                                         G);
  main_kernel<<<1024, 512, SMEM_TOTAL, stream>>>(law_lens, lawsB, conB, G,
                                                 cnorm, out);
}